// Round 10
// baseline (130.106 us; speedup 1.0000x reference)
//
#include <hip/hip_runtime.h>

// WorldModel: N=8192
//   out_h[c] = action[c] * (1 - prod_r (1 - holding[r]*D[r][c]))
//   out_d[r][c] = p1 + p2 - p1*p2,  p1 = D[r][c]*(1-action[c]), p2 = D[r][c]*(1-holding[r])
//
// R10: proven config = NT-load + CACHED-store (R9, -10%). This round:
// ROWS 32->64 (halves ws round-trip 16MB->8MB, halves prologue count),
// COLSPLIT=4 / THREADS=512 keeps 512 blocks (4 blocks/CU), unroll 8.
// Reduce: K=128 partials, same parallel scheme.

typedef float v4f __attribute__((ext_vector_type(4)));

template<int ROWS, int THREADS, int COLSPLIT>
__global__ __launch_bounds__(THREADS, 8) void wm_split(
    const float* __restrict__ action,
    const float* __restrict__ holding,
    const float* __restrict__ dominos,
    float* __restrict__ out_d,     // [n*n]
    float* __restrict__ ws,        // [n/ROWS][n] partial column products
    int n)
{
    __shared__ float sh_h[ROWS];
    __shared__ float sh_hr[ROWS];

    const int tid = threadIdx.x;
    const int b   = blockIdx.x;
    const int rg  = b / COLSPLIT;
    const int ch  = b % COLSPLIT;
    const int r0  = rg * ROWS;
    const int c0  = ch * (n / COLSPLIT);

    if (tid < ROWS) {
        const float h = holding[r0 + tid];
        sh_h[tid]  = h;
        sh_hr[tid] = 1.0f - h;
    }
    __syncthreads();

    const v4f ones = {1.0f, 1.0f, 1.0f, 1.0f};
    const int  c   = c0 + tid * 4;

    const v4f av   = *reinterpret_cast<const v4f*>(action + c);
    const v4f ac   = ones - av;
    v4f prod       = ones;

    const float* src = dominos + (size_t)r0 * (size_t)n + c;
    float*       dst = out_d   + (size_t)r0 * (size_t)n + c;

    #pragma unroll 8
    for (int r = 0; r < ROWS; ++r) {
        const float h  = sh_h[r];
        const float hr = sh_hr[r];

        const v4f v = __builtin_nontemporal_load(
            reinterpret_cast<const v4f*>(src + (size_t)r * (size_t)n));

        prod *= (ones - v * h);              // prod *= (1 - h*D)
        const v4f p1 = v * ac;
        const v4f p2 = v * hr;
        const v4f o  = p1 + p2 - p1 * p2;    // noisy-OR
        *reinterpret_cast<v4f*>(dst + (size_t)r * (size_t)n) = o;  // cached
    }

    *reinterpret_cast<v4f*>(ws + (size_t)rg * (size_t)n + c) = prod;
}

// Reduce: K = n/ROWS partials per column. KSPLIT x COLS threads.
template<int KSPLIT, int COLS>
__global__ __launch_bounds__(KSPLIT * COLS) void wm_reduce_par(
    const float* __restrict__ action,
    const float* __restrict__ ws,   // [K][n]
    float* __restrict__ out_h,      // [n]
    int n, int K)
{
    __shared__ float sh[KSPLIT][COLS];

    const int tid = threadIdx.x;
    const int cl  = tid % COLS;
    const int kk  = tid / COLS;
    const int c   = blockIdx.x * COLS + cl;

    const int kchunk = K / KSPLIT;
    float prod = 1.0f;
    #pragma unroll 4
    for (int k = kk * kchunk; k < (kk + 1) * kchunk; ++k) {
        prod *= ws[(size_t)k * (size_t)n + c];
    }
    sh[kk][cl] = prod;
    __syncthreads();

    if (kk == 0) {
        float p = sh[0][cl];
        #pragma unroll
        for (int j = 1; j < KSPLIT; ++j) p *= sh[j][cl];
        out_h[c] = action[c] * (1.0f - p);
    }
}

// ---------- generic fallbacks (non-8192 geometry) ----------

__global__ __launch_bounds__(256) void wm_main_generic(
    const float* __restrict__ action,
    const float* __restrict__ holding,
    const float* __restrict__ dominos,
    float* __restrict__ out_d,
    float* __restrict__ ws,        // or nullptr
    float* __restrict__ out_h,     // used when ws == nullptr
    int n, int rows_per_chunk)
{
    const int c4 = (blockIdx.x * blockDim.x + threadIdx.x) * 4;
    if (c4 >= n) return;

    const int r0 = blockIdx.y * rows_per_chunk;
    int r1 = r0 + rows_per_chunk;
    if (r1 > n) r1 = n;

    const float4 av = *reinterpret_cast<const float4*>(action + c4);
    const float4 ac = make_float4(1.0f - av.x, 1.0f - av.y, 1.0f - av.z, 1.0f - av.w);

    v4f prod = {1.0f, 1.0f, 1.0f, 1.0f};

    #pragma unroll 8
    for (int r = r0; r < r1; ++r) {
        const float h  = holding[r];
        const float hr = 1.0f - h;
        const size_t off = (size_t)r * (size_t)n + (size_t)c4;
        const v4f v = __builtin_nontemporal_load(
            reinterpret_cast<const v4f*>(dominos + off));

        prod.x *= fmaf(-h, v.x, 1.0f);
        prod.y *= fmaf(-h, v.y, 1.0f);
        prod.z *= fmaf(-h, v.z, 1.0f);
        prod.w *= fmaf(-h, v.w, 1.0f);

        v4f o;
        { float p1 = v.x * ac.x, p2 = v.x * hr; o.x = fmaf(-p1, p2, p1 + p2); }
        { float p1 = v.y * ac.y, p2 = v.y * hr; o.y = fmaf(-p1, p2, p1 + p2); }
        { float p1 = v.z * ac.z, p2 = v.z * hr; o.z = fmaf(-p1, p2, p1 + p2); }
        { float p1 = v.w * ac.w, p2 = v.w * hr; o.w = fmaf(-p1, p2, p1 + p2); }
        *reinterpret_cast<v4f*>(out_d + off) = o;
    }

    if (ws) {
        *reinterpret_cast<v4f*>(ws + (size_t)blockIdx.y * (size_t)n + (size_t)c4) = prod;
    } else {
        float4 oh;
        oh.x = av.x * (1.0f - prod.x);
        oh.y = av.y * (1.0f - prod.y);
        oh.z = av.z * (1.0f - prod.z);
        oh.w = av.w * (1.0f - prod.w);
        *reinterpret_cast<float4*>(out_h + c4) = oh;
    }
}

__global__ __launch_bounds__(256) void wm_reduce_col(
    const float* __restrict__ action,
    const float* __restrict__ ws,   // [K][n]
    float* __restrict__ out_h,      // [n]
    int n, int K)
{
    const int c = blockIdx.x * blockDim.x + threadIdx.x;
    if (c >= n) return;

    float prod = 1.0f;
    #pragma unroll 4
    for (int k = 0; k < K; ++k) {
        prod *= ws[(size_t)k * (size_t)n + c];
    }
    out_h[c] = action[c] * (1.0f - prod);
}

extern "C" void kernel_launch(void* const* d_in, const int* in_sizes, int n_in,
                              void* d_out, int out_size, void* d_ws, size_t ws_size,
                              hipStream_t stream)
{
    const int n = in_sizes[0];                 // 8192
    const float* action  = (const float*)d_in[0];
    const float* holding = (const float*)d_in[1];
    const float* dominos = (const float*)d_in[2];

    float* out_h = (float*)d_out;              // [n]
    float* out_d = out_h + n;                  // [n*n]
    float* ws    = (float*)d_ws;

    constexpr int ROWS     = 64;
    constexpr int THREADS  = 512;
    constexpr int COLSPLIT = 4;
    constexpr int KSPLIT   = 8;
    constexpr int COLS     = 32;

    const int K = n / ROWS;                    // 128 for n=8192

    const bool fast =
        (n % ROWS == 0) &&
        (n / COLSPLIT == THREADS * 4) &&       // exact column-chunk coverage
        (K % KSPLIT == 0) &&
        (n % COLS == 0) &&
        ((size_t)K * (size_t)n * sizeof(float) <= ws_size);

    if (fast) {
        const int nblocks = K * COLSPLIT;      // 512
        wm_split<ROWS, THREADS, COLSPLIT><<<nblocks, THREADS, 0, stream>>>(
            action, holding, dominos, out_d, ws, n);
        wm_reduce_par<KSPLIT, COLS><<<n / COLS, KSPLIT * COLS, 0, stream>>>(
            action, ws, out_h, n, K);
    } else {
        const int cols_per_block = 256 * 4;
        const int cb = (n + cols_per_block - 1) / cols_per_block;

        const size_t max_rb_ws = ws_size / ((size_t)n * sizeof(float));
        int rb = 256;
        while (rb > 1 && ((size_t)rb > max_rb_ws || rb > n)) rb >>= 1;
        if (max_rb_ws < 1) rb = 1;

        const int rows_per_chunk = (n + rb - 1) / rb;
        const bool use_ws = (rb > 1);

        dim3 grid1(cb, rb);
        wm_main_generic<<<grid1, 256, 0, stream>>>(action, holding, dominos,
                                                   out_d,
                                                   use_ws ? ws : nullptr,
                                                   out_h,
                                                   n, rows_per_chunk);
        if (use_ws) {
            wm_reduce_col<<<(n + 255) / 256, 256, 0, stream>>>(
                action, ws, out_h, n, rb);
        }
    }
}

// Round 11
// 99.469 us; speedup vs baseline: 1.3080x; 1.3080x over previous
//
#include <hip/hip_runtime.h>

// WorldModel: N=8192
//   out_h[c] = action[c] * (1 - prod_r (1 - holding[r]*D[r][c]))
//   out_d[r][c] = p1 + p2 - p1*p2,  p1 = D[r][c]*(1-action[c]), p2 = D[r][c]*(1-holding[r])
//
// R11: pure revert to R9 (99.7 us). R10 (ROWS=64/512thr/COLSPLIT=4/unroll8)
// regressed 30%: __launch_bounds__(512,8) caps VGPRs at 64, unroll-8 needs
// >32 VGPRs of in-flight load data alone -> scratch spill on a stream kernel.
// Proven config: NT-load (read-once, no L2 allocate) + CACHED store (L2
// write-back coalescing, like the 7 TB/s fill), 512 blocks x 1024 threads,
// ROWS=32, unroll 4, parallel LDS-tree reduce. Main kernel ~5.8 TB/s = 92%
// of the 6.29 TB/s copy ceiling for a 1:1 R/W stream.

typedef float v4f __attribute__((ext_vector_type(4)));

template<int ROWS, int THREADS, int COLSPLIT>
__global__ __launch_bounds__(THREADS, 8) void wm_split(
    const float* __restrict__ action,
    const float* __restrict__ holding,
    const float* __restrict__ dominos,
    float* __restrict__ out_d,     // [n*n]
    float* __restrict__ ws,        // [n/ROWS][n] partial column products
    int n)
{
    __shared__ float sh_h[ROWS];
    __shared__ float sh_hr[ROWS];

    const int tid = threadIdx.x;
    const int b   = blockIdx.x;
    const int rg  = b / COLSPLIT;
    const int ch  = b % COLSPLIT;
    const int r0  = rg * ROWS;
    const int c0  = ch * (n / COLSPLIT);

    if (tid < ROWS) {
        const float h = holding[r0 + tid];
        sh_h[tid]  = h;
        sh_hr[tid] = 1.0f - h;
    }
    __syncthreads();

    const v4f ones = {1.0f, 1.0f, 1.0f, 1.0f};
    const int  c   = c0 + tid * 4;

    const v4f av   = *reinterpret_cast<const v4f*>(action + c);
    const v4f ac   = ones - av;
    v4f prod       = ones;

    const float* src = dominos + (size_t)r0 * (size_t)n + c;
    float*       dst = out_d   + (size_t)r0 * (size_t)n + c;

    #pragma unroll 4
    for (int r = 0; r < ROWS; ++r) {
        const float h  = sh_h[r];
        const float hr = sh_hr[r];

        const v4f v = __builtin_nontemporal_load(
            reinterpret_cast<const v4f*>(src + (size_t)r * (size_t)n));

        prod *= (ones - v * h);              // prod *= (1 - h*D)
        const v4f p1 = v * ac;
        const v4f p2 = v * hr;
        const v4f o  = p1 + p2 - p1 * p2;    // noisy-OR
        *reinterpret_cast<v4f*>(dst + (size_t)r * (size_t)n) = o;  // cached
    }

    *reinterpret_cast<v4f*>(ws + (size_t)rg * (size_t)n + c) = prod;
}

// Reduce: K = n/ROWS partials per column. 256 threads = KSPLIT(8) x 32 cols.
template<int KSPLIT, int COLS>
__global__ __launch_bounds__(KSPLIT * COLS) void wm_reduce_par(
    const float* __restrict__ action,
    const float* __restrict__ ws,   // [K][n]
    float* __restrict__ out_h,      // [n]
    int n, int K)
{
    __shared__ float sh[KSPLIT][COLS];

    const int tid = threadIdx.x;
    const int cl  = tid % COLS;
    const int kk  = tid / COLS;
    const int c   = blockIdx.x * COLS + cl;

    const int kchunk = K / KSPLIT;
    float prod = 1.0f;
    #pragma unroll 4
    for (int k = kk * kchunk; k < (kk + 1) * kchunk; ++k) {
        prod *= ws[(size_t)k * (size_t)n + c];
    }
    sh[kk][cl] = prod;
    __syncthreads();

    if (kk == 0) {
        float p = sh[0][cl];
        #pragma unroll
        for (int j = 1; j < KSPLIT; ++j) p *= sh[j][cl];
        out_h[c] = action[c] * (1.0f - p);
    }
}

// ---------- generic fallbacks (non-8192 geometry) ----------

__global__ __launch_bounds__(256) void wm_main_generic(
    const float* __restrict__ action,
    const float* __restrict__ holding,
    const float* __restrict__ dominos,
    float* __restrict__ out_d,
    float* __restrict__ ws,        // or nullptr
    float* __restrict__ out_h,     // used when ws == nullptr
    int n, int rows_per_chunk)
{
    const int c4 = (blockIdx.x * blockDim.x + threadIdx.x) * 4;
    if (c4 >= n) return;

    const int r0 = blockIdx.y * rows_per_chunk;
    int r1 = r0 + rows_per_chunk;
    if (r1 > n) r1 = n;

    const float4 av = *reinterpret_cast<const float4*>(action + c4);
    const float4 ac = make_float4(1.0f - av.x, 1.0f - av.y, 1.0f - av.z, 1.0f - av.w);

    v4f prod = {1.0f, 1.0f, 1.0f, 1.0f};

    #pragma unroll 8
    for (int r = r0; r < r1; ++r) {
        const float h  = holding[r];
        const float hr = 1.0f - h;
        const size_t off = (size_t)r * (size_t)n + (size_t)c4;
        const v4f v = __builtin_nontemporal_load(
            reinterpret_cast<const v4f*>(dominos + off));

        prod.x *= fmaf(-h, v.x, 1.0f);
        prod.y *= fmaf(-h, v.y, 1.0f);
        prod.z *= fmaf(-h, v.z, 1.0f);
        prod.w *= fmaf(-h, v.w, 1.0f);

        v4f o;
        { float p1 = v.x * ac.x, p2 = v.x * hr; o.x = fmaf(-p1, p2, p1 + p2); }
        { float p1 = v.y * ac.y, p2 = v.y * hr; o.y = fmaf(-p1, p2, p1 + p2); }
        { float p1 = v.z * ac.z, p2 = v.z * hr; o.z = fmaf(-p1, p2, p1 + p2); }
        { float p1 = v.w * ac.w, p2 = v.w * hr; o.w = fmaf(-p1, p2, p1 + p2); }
        *reinterpret_cast<v4f*>(out_d + off) = o;
    }

    if (ws) {
        *reinterpret_cast<v4f*>(ws + (size_t)blockIdx.y * (size_t)n + (size_t)c4) = prod;
    } else {
        float4 oh;
        oh.x = av.x * (1.0f - prod.x);
        oh.y = av.y * (1.0f - prod.y);
        oh.z = av.z * (1.0f - prod.z);
        oh.w = av.w * (1.0f - prod.w);
        *reinterpret_cast<float4*>(out_h + c4) = oh;
    }
}

__global__ __launch_bounds__(256) void wm_reduce_col(
    const float* __restrict__ action,
    const float* __restrict__ ws,   // [K][n]
    float* __restrict__ out_h,      // [n]
    int n, int K)
{
    const int c = blockIdx.x * blockDim.x + threadIdx.x;
    if (c >= n) return;

    float prod = 1.0f;
    #pragma unroll 4
    for (int k = 0; k < K; ++k) {
        prod *= ws[(size_t)k * (size_t)n + c];
    }
    out_h[c] = action[c] * (1.0f - prod);
}

extern "C" void kernel_launch(void* const* d_in, const int* in_sizes, int n_in,
                              void* d_out, int out_size, void* d_ws, size_t ws_size,
                              hipStream_t stream)
{
    const int n = in_sizes[0];                 // 8192
    const float* action  = (const float*)d_in[0];
    const float* holding = (const float*)d_in[1];
    const float* dominos = (const float*)d_in[2];

    float* out_h = (float*)d_out;              // [n]
    float* out_d = out_h + n;                  // [n*n]
    float* ws    = (float*)d_ws;

    constexpr int ROWS     = 32;
    constexpr int THREADS  = 1024;
    constexpr int COLSPLIT = 2;
    constexpr int KSPLIT   = 8;
    constexpr int COLS     = 32;

    const int K = n / ROWS;                    // 256 for n=8192

    const bool fast =
        (n % ROWS == 0) &&
        (n / COLSPLIT == THREADS * 4) &&       // exact column-half coverage
        (K % KSPLIT == 0) &&
        (n % COLS == 0) &&
        ((size_t)K * (size_t)n * sizeof(float) <= ws_size);

    if (fast) {
        const int nblocks = K * COLSPLIT;      // 512
        wm_split<ROWS, THREADS, COLSPLIT><<<nblocks, THREADS, 0, stream>>>(
            action, holding, dominos, out_d, ws, n);
        wm_reduce_par<KSPLIT, COLS><<<n / COLS, KSPLIT * COLS, 0, stream>>>(
            action, ws, out_h, n, K);
    } else {
        const int cols_per_block = 256 * 4;
        const int cb = (n + cols_per_block - 1) / cols_per_block;

        const size_t max_rb_ws = ws_size / ((size_t)n * sizeof(float));
        int rb = 256;
        while (rb > 1 && ((size_t)rb > max_rb_ws || rb > n)) rb >>= 1;
        if (max_rb_ws < 1) rb = 1;

        const int rows_per_chunk = (n + rb - 1) / rb;
        const bool use_ws = (rb > 1);

        dim3 grid1(cb, rb);
        wm_main_generic<<<grid1, 256, 0, stream>>>(action, holding, dominos,
                                                   out_d,
                                                   use_ws ? ws : nullptr,
                                                   out_h,
                                                   n, rows_per_chunk);
        if (use_ws) {
            wm_reduce_col<<<(n + 255) / 256, 256, 0, stream>>>(
                action, ws, out_h, n, rb);
        }
    }
}